// Round 10
// baseline (396.384 us; speedup 1.0000x reference)
//
#include <hip/hip_runtime.h>
#include <math.h>

typedef __bf16 bfrag __attribute__((ext_vector_type(8)));
typedef __bf16 bf16x4 __attribute__((ext_vector_type(4)));
typedef __bf16 bf16x8 __attribute__((ext_vector_type(8)));
typedef float f32x4 __attribute__((ext_vector_type(4)));

// Problem constants
#define BN 32
#define HH 300
#define WW 300
#define HW 90000
#define NPX (BN * HW)

// Output tile 16 rows x 32 cols
#define GX 10   // ceil(300/32)
#define GY 19   // ceil(300/16)
#define CPX 612         // 18*34 c-tile pixels
#define XPX 720         // 20*36 staged pixels
#define CWSTRIDE 4896   // 612*8 shorts per channel-block array (fallback)

// ---------------- workspace layout ----------------
#define P5I_BYTE_OFF   0
#define P10I_BYTE_OFF  1843200
#define P15I_BYTE_OFF  2304000
#define CWB_BYTE_OFF   2508800
#define GWB_BYTE_OFF   2524160
#define STAT_BYTE_OFF  2531328
#define SS_BYTE_OFF    2539520
#define XBF_BYTE_OFF   2539584
#define XBF_END        (XBF_BYTE_OFF + (size_t)NPX * 16)   // 48,619,584

// ---------------- k_fused5 LDS layout (bytes) ------------------------------
#define XU4_OFF   0        // [20*36 px][8ch] bf16 = 11520
#define P5_OFF4   11520    // 5 rows x 8 cols x 16B = 640
#define P10_OFF4  12160    // 3 x 5 x 16B = 240
#define P15_OFF4  12400    // 3 x 4 x 16B = 192
#define CW4_OFF   12592    // [3][612 px][8ch] bf16 = 29376
#define LDS4_SIZE 41968    // + LUTs 672B -> 42.6KB -> 3 blocks/CU

__device__ __forceinline__ short f2bf(float f) {
    union { float f; unsigned u; } v;
    v.f = f;
    unsigned r = v.u + 0x7FFF + ((v.u >> 16) & 1);
    return (short)(r >> 16);
}

__device__ __forceinline__ float bf2f(unsigned short s) {
    union { unsigned u; float f; } v;
    v.u = ((unsigned)s) << 16;
    return v.f;
}

// ---------------------------------------------------------------------------
// setup: cB[s][n16][tap10][ci16] (n>=8 or tap==9 -> 0);
//        gB[n16][blk28][cj8] (blk>=27 -> 0); zero stat bins
// ---------------------------------------------------------------------------
__device__ __forceinline__ void setup_body(int gid, int gstride,
                                           const float* __restrict__ w5,
                                           const float* __restrict__ w10,
                                           const float* __restrict__ w15,
                                           const float* __restrict__ gw,
                                           const float* __restrict__ mw,
                                           short* __restrict__ cBg,
                                           short* __restrict__ gBg,
                                           double* __restrict__ stats) {
    for (int idx = gid; idx < 7680; idx += gstride) {
        int s = idx / 2560, rem = idx % 2560;
        int n = rem / 160, r2 = rem % 160;
        int tap = r2 / 16, ci = r2 % 16;
        float v = 0.f;
        if (n < 8 && tap < 9) {
            const float* W = (s == 0) ? w5 : ((s == 1) ? w10 : w15);
            v = W[(n * 16 + ci) * 9 + tap];
        }
        cBg[idx] = f2bf(v);
    }
    for (int idx = gid; idx < 3584; idx += gstride) {
        int n = idx / 224, r2 = idx % 224;
        int blk = r2 / 8, cj = r2 % 8;
        float v = 0.f;
        if (blk < 27) {
            int tap = blk / 3, ci24 = (blk % 3) * 8 + cj;
            if (n < 8) v = gw[(n * 24 + ci24) * 9 + tap];
            else       v = mw[((n - 8) * 24 + ci24) * 9 + tap];
        }
        gBg[idx] = f2bf(v);
    }
    for (int idx = gid; idx < 16 * 64; idx += gstride) stats[idx] = 0.0;
}

__global__ void k_setup(const float* __restrict__ w5, const float* __restrict__ w10,
                        const float* __restrict__ w15, const float* __restrict__ gw,
                        const float* __restrict__ mw, short* __restrict__ cBg,
                        short* __restrict__ gBg, double* __restrict__ stats) {
    setup_body(threadIdx.x, 256, w5, w10, w15, gw, mw, cBg, gBg, stats);
}

// ---------------------------------------------------------------------------
// k_prepAll: ONE dispatch: 30x30 region per block. f32 x -> LDS ->
// (a) channel-interleaved bf16 xbf write, (b) p5/p10/p15 pooled maps
// (pooled from f32, closer to reference). Blocks (y==0,x<16) fold in setup.
// LDS 30KB -> 5 blocks/CU.
// ---------------------------------------------------------------------------
__global__ __launch_bounds__(256) void k_prepAll(const float* __restrict__ x,
                                                 unsigned short* __restrict__ xbf,
                                                 unsigned short* __restrict__ p5i,
                                                 unsigned short* __restrict__ p10i,
                                                 unsigned short* __restrict__ p15i,
                                                 const float* __restrict__ w5,
                                                 const float* __restrict__ w10,
                                                 const float* __restrict__ w15,
                                                 const float* __restrict__ gw,
                                                 const float* __restrict__ mw,
                                                 short* __restrict__ cBg,
                                                 short* __restrict__ gBg,
                                                 double* __restrict__ stats) {
    __shared__ float tf[8][900];    // 30x30 px x 8ch f32 = 28.8KB
    __shared__ float p5t[36][8];
    const int b = blockIdx.y, t = threadIdx.x;
    const int bi = blockIdx.x / 10, bj = blockIdx.x % 10;
    const float* xb0 = x + (size_t)b * 8 * HW + (bi * 30) * WW + bj * 30;

    for (int idx = t; idx < 3600; idx += 256) {   // float2 loads: 8ch x 30r x 15
        int ch = idx / 450, rem = idx % 450;
        int r = rem / 15, c2 = rem % 15;
        float2 v = *(const float2*)&xb0[(size_t)ch * HW + r * WW + 2 * c2];
        tf[ch][r * 30 + 2 * c2] = v.x;
        tf[ch][r * 30 + 2 * c2 + 1] = v.y;
    }
    if (blockIdx.y == 0 && blockIdx.x < 16)
        setup_body(blockIdx.x * 256 + t, 4096, w5, w10, w15, gw, mw, cBg, gBg, stats);
    __syncthreads();

    for (int idx = t; idx < 900; idx += 256) {    // interleaved bf16 x copy
        int r = idx / 30, c = idx - r * 30;
        bf16x8 pk;
#pragma unroll
        for (int ch = 0; ch < 8; ch++) pk[ch] = (__bf16)tf[ch][idx];
        *(bf16x8*)&xbf[((size_t)b * HW + (bi * 30 + r) * WW + bj * 30 + c) * 8] = pk;
    }
    if (t < 36) {                                  // p5: 6x6 cells
        int pi = t / 6, pj = t - (t / 6) * 6;
        float s[8] = {0.f, 0.f, 0.f, 0.f, 0.f, 0.f, 0.f, 0.f};
#pragma unroll
        for (int ch = 0; ch < 8; ch++)
#pragma unroll
            for (int u = 0; u < 5; u++)
#pragma unroll
                for (int v = 0; v < 5; v++) s[ch] += tf[ch][(pi * 5 + u) * 30 + pj * 5 + v];
        bf16x8 pk;
#pragma unroll
        for (int ch = 0; ch < 8; ch++) {
            float av = s[ch] * 0.04f;
            p5t[t][ch] = av;
            pk[ch] = (__bf16)av;
        }
        *(bf16x8*)&p5i[((size_t)b * 3600 + (bi * 6 + pi) * 60 + bj * 6 + pj) * 8] = pk;
    }
    __syncthreads();
    if (t < 9) {        // p10: 3x3 cells = 2x2 p5 (exact mean)
        int pi = t / 3, pj = t - (t / 3) * 3;
        bf16x8 pk;
#pragma unroll
        for (int ch = 0; ch < 8; ch++) {
            float s = p5t[(2 * pi) * 6 + 2 * pj][ch] + p5t[(2 * pi) * 6 + 2 * pj + 1][ch] +
                      p5t[(2 * pi + 1) * 6 + 2 * pj][ch] + p5t[(2 * pi + 1) * 6 + 2 * pj + 1][ch];
            pk[ch] = (__bf16)(s * 0.25f);
        }
        *(bf16x8*)&p10i[((size_t)b * 900 + (bi * 3 + pi) * 30 + bj * 3 + pj) * 8] = pk;
    } else if (t < 13) {  // p15: 2x2 cells = 3x3 p5
        int i2 = t - 9;
        int pi = i2 >> 1, pj = i2 & 1;
        bf16x8 pk;
#pragma unroll
        for (int ch = 0; ch < 8; ch++) {
            float s = 0.f;
#pragma unroll
            for (int u = 0; u < 3; u++)
#pragma unroll
                for (int v = 0; v < 3; v++) s += p5t[(3 * pi + u) * 6 + 3 * pj + v][ch];
            pk[ch] = (__bf16)(s * (1.f / 9.f));
        }
        *(bf16x8*)&p15i[((size_t)b * 400 + (bi * 2 + pi) * 20 + bj * 2 + pj) * 8] = pk;
    }
}

// ---------------------------------------------------------------------------
// c_phase5: conv([x, up_s]) -> cw buffer. Up addresses via per-block LDS LUTs
// (lr[i] = patch row byte base for tile-row i, lc[j] = col byte offset) —
// replaces 6 magic divisions/group with 6 broadcast LDS reads. LUT entries
// reproduce the HW-verified round-8/9 division arithmetic exactly.
// ---------------------------------------------------------------------------
__device__ __forceinline__ void c_phase5(char* LDSp, int cwOff,
                                         const unsigned short* __restrict__ cBs,
                                         const float* __restrict__ bias,
                                         const int* lr, const int* lc,
                                         int r0, int c0, int lane, int wid, bool edge) {
    constexpr int T0[5] = {0, 2, 4, 6, 8};   // qh=0 taps
    constexpr int T1[5] = {1, 3, 5, 7, 8};   // qh=1 taps (9 -> clamp 8 for addr)
    const int n = lane & 15, quad = lane >> 4;
    const int qh = quad >> 1, ql = quad & 1;
    bfrag wfr[5];
#pragma unroll
    for (int km = 0; km < 5; km++) {
        int tapw = km * 2 + qh;                 // 9 -> zero row in cB
        wfr[km] = *(const bfrag*)&cBs[(n * 10 + tapw) * 16 + ql * 8];
    }
    float bO[4];
#pragma unroll
    for (int r = 0; r < 4; r++) bO[r] = bias[(quad & 1) * 4 + r];

    for (int g = wid; g < 39; g += 4) {
        int px = g * 16 + n;
        if (px > 611) px = 611;                 // dup lanes write same value
        int rp = (int)((unsigned)px / 34u);
        int cp = px - rp * 34;
        int xb = (rp * 36 + cp) * 16;
        int lr0 = lr[rp], lr1 = lr[rp + 1], lr2 = lr[rp + 2];
        int lc0 = lc[cp], lc1 = lc[cp + 1], lc2 = lc[cp + 2];
        f32x4 acc = {0.f, 0.f, 0.f, 0.f};
#pragma unroll
        for (int km = 0; km < 5; km++) {
            constexpr int d0r[5] = {0, 0, 1, 2, 2}, d0c[5] = {0, 2, 1, 0, 2};
            constexpr int d1r[5] = {0, 1, 1, 2, 2}, d1c[5] = {1, 0, 2, 1, 2};
            int dr = qh ? d1r[km] : d0r[km];    // compile-time pair -> 1 select
            int dc = qh ? d1c[km] : d0c[km];
            int rA = (dr == 0) ? lr0 : ((dr == 1) ? lr1 : lr2);
            int cA = (dc == 0) ? lc0 : ((dc == 1) ? lc1 : lc2);
            int au = rA + cA;
            int xo = qh ? ((T1[km] / 3) * 36 + T1[km] % 3) * 16
                        : ((T0[km] / 3) * 36 + T0[km] % 3) * 16;
            int ax = xb + xo;
            int ad = ql ? au : ax;
            acc = __builtin_amdgcn_mfma_f32_16x16x32_bf16(
                wfr[km], *(const bfrag*)(LDSp + ad), acc, 0, 0, 0);
        }
        if (quad < 2) {                          // channels quad*4+reg (0..7)
            bf16x4 pk;
#pragma unroll
            for (int r = 0; r < 4; r++) pk[r] = (__bf16)(acc[r] + bO[r]);
            if (edge) {
                int ra = r0 - 1 + rp, ca = c0 - 1 + cp;
                if (ra < 0 || ra >= HH || ca < 0 || ca >= WW) {
#pragma unroll
                    for (int r = 0; r < 4; r++) pk[r] = (__bf16)0.f;
                }
            }
            *(bf16x4*)(LDSp + cwOff + px * 16 + quad * 8) = pk;
        }
    }
}

// ---------------------------------------------------------------------------
// k_fused5: 16x32 tile, round-9 structure + LUT addressing. 2 barriers,
// LDS 42.6KB -> 3 blocks/CU, no persistent cross-phase accumulators.
// ---------------------------------------------------------------------------
__global__ __launch_bounds__(256, 3) void k_fused5(
    const unsigned short* __restrict__ xbf,
    const unsigned short* __restrict__ p5i, const unsigned short* __restrict__ p10i,
    const unsigned short* __restrict__ p15i,
    const unsigned short* __restrict__ cBg, const unsigned short* __restrict__ gBg,
    const float* __restrict__ b5, const float* __restrict__ b10, const float* __restrict__ b15,
    const float* __restrict__ gb, const float* __restrict__ mb,
    float* __restrict__ out, double* __restrict__ stats) {
    __shared__ __align__(16) char LDS[LDS4_SIZE];
    __shared__ int lutR[3][20];
    __shared__ int lutC[3][36];

    const int b = blockIdx.z;
    const int r0 = blockIdx.y * 16, c0 = blockIdx.x * 32;
    const int t = threadIdx.x, lane = t & 63, wid = t >> 6;
    const bool edge = (blockIdx.x == 0) | (blockIdx.x == GX - 1) |
                      (blockIdx.y == 0) | (blockIdx.y == GY - 1);

    const int pr0_5 = (r0 + 3) / 5, pc0_5 = (c0 + 3) / 5;
    const int pr0_10 = (r0 + 8) / 10, pc0_10 = (c0 + 8) / 10;
    const int pr0_15 = (r0 + 13) / 15, pc0_15 = (c0 + 13) / 15;

    // stage x tile (720 x uint4)
#pragma unroll
    for (int it = 0; it < 3; it++) {
        int idx = t + 256 * it;
        if (idx < XPX) {
            int i = idx / 36, j = idx - i * 36;
            int ra = r0 - 2 + i, ca = c0 - 2 + j;
            uint4 v = {0u, 0u, 0u, 0u};
            if (ra >= 0 && ra < HH && ca >= 0 && ca < WW)
                v = *(const uint4*)&xbf[((size_t)b * HW + ra * WW + ca) * 8];
            *(uint4*)(LDS + XU4_OFF + idx * 16) = v;
        }
    }
    // stage pooled patches (67 x uint4), zero-filled outside pooled grid
    if (t < 67) {
        const unsigned short* src;
        int off;
        bool valid;
        if (t < 40) {
            int a = t >> 3, cc = t & 7;
            int ci = pr0_5 - 1 + a, cj = pc0_5 - 1 + cc;
            valid = (ci >= 0) && (ci < 60) && (cj >= 0) && (cj < 60);
            src = p5i + ((size_t)b * 3600 + ci * 60 + cj) * 8;
            off = P5_OFF4 + t * 16;
        } else if (t < 55) {
            int i2 = t - 40;
            int a = i2 / 5, cc = i2 % 5;
            int ci = pr0_10 - 1 + a, cj = pc0_10 - 1 + cc;
            valid = (ci >= 0) && (ci < 30) && (cj >= 0) && (cj < 30);
            src = p10i + ((size_t)b * 900 + ci * 30 + cj) * 8;
            off = P10_OFF4 + i2 * 16;
        } else {
            int i2 = t - 55;
            int a = i2 >> 2, cc = i2 & 3;
            int ci = pr0_15 - 1 + a, cj = pc0_15 - 1 + cc;
            valid = (ci >= 0) && (ci < 20) && (cj >= 0) && (cj < 20);
            src = p15i + ((size_t)b * 400 + ci * 20 + cj) * 8;
            off = P15_OFF4 + i2 * 16;
        }
        uint4 v = {0u, 0u, 0u, 0u};
        if (valid) v = *(const uint4*)src;
        *(uint4*)(LDS + off) = v;
    }
    // build address LUTs (exactly the round-8/9 verified arithmetic)
    if (t < 168) {
        int set = t / 56, e = t % 56;
        int K = (set == 0) ? 5 : ((set == 1) ? 10 : 15);
        int PC = (set == 0) ? 8 : ((set == 1) ? 5 : 4);
        int pOff = (set == 0) ? P5_OFF4 : ((set == 1) ? P10_OFF4 : P15_OFF4);
        int pr = (set == 0) ? pr0_5 : ((set == 1) ? pr0_10 : pr0_15);
        int pc = (set == 0) ? pc0_5 : ((set == 1) ? pc0_10 : pc0_15);
        if (e < 20)
            lutR[set][e] = (int)((unsigned)(r0 - 2 + e + K) / (unsigned)K) * (PC * 16)
                           + pOff - pr * (PC * 16);
        else {
            int j = e - 20;
            lutC[set][j] = (int)((unsigned)(c0 - 2 + j + K) / (unsigned)K) * 16 - pc * 16;
        }
    }
    __syncthreads();

    // three c-phases, disjoint cwS regions, no barriers between them
    c_phase5(LDS, CW4_OFF,         cBg,        b5,  lutR[0], lutC[0], r0, c0, lane, wid, edge);
    c_phase5(LDS, CW4_OFF + 9792,  cBg + 2560, b10, lutR[1], lutC[1], r0, c0, lane, wid, edge);
    c_phase5(LDS, CW4_OFF + 19584, cBg + 5120, b15, lutR[2], lutC[2], r0, c0, lane, wid, edge);
    __syncthreads();

    // gate phase: A = gB weights (G 0-7 / M 8-15), B = cwS pixels across all
    // 27 (tap, scale) blocks; sigmoid on idle M-lanes; pair via shfl_xor(32).
    const int n = lane & 15, quad = lane >> 4;
    bfrag gfr[7];
    int goff[7];
#pragma unroll
    for (int km = 0; km < 7; km++) {
        int blkw = km * 4 + quad;               // 27 -> zero block in gB
        int blka = (blkw > 26) ? 26 : blkw;     // address clamp only
        gfr[km] = *(const bfrag*)&gBg[(n * 28 + blkw) * 8];
        int tap = blka / 3, cig = blka - tap * 3;
        goff[km] = cig * 9792 + ((tap / 3) * 34 + tap % 3) * 16;   // bytes
    }
    float gO[4], mO[4];
#pragma unroll
    for (int r = 0; r < 4; r++) {
        gO[r] = gb[(quad & 1) * 4 + r];
        mO[r] = mb[(quad & 1) * 4 + r];
    }
    float ls[4] = {0.f, 0.f, 0.f, 0.f}, ls2[4] = {0.f, 0.f, 0.f, 0.f};

    for (int g = wid; g < 32; g += 4) {
        int px = g * 16 + n;
        int rr = px >> 5, cc = px & 31;
        int off0 = CW4_OFF + (rr * 34 + cc) * 16;
        f32x4 acc = {0.f, 0.f, 0.f, 0.f};
#pragma unroll
        for (int km = 0; km < 7; km++)
            acc = __builtin_amdgcn_mfma_f32_16x16x32_bf16(
                gfr[km], *(const bfrag*)(LDS + off0 + goff[km]), acc, 0, 0, 0);
        int ra = r0 + rr, ca = c0 + cc;
        bool wr = !edge || (ra < HH && ca < WW);
#pragma unroll
        for (int reg = 0; reg < 4; reg++) {
            float val;
            if (quad < 2) val = acc[reg] + gO[reg];
            else          val = __builtin_amdgcn_rcpf(1.f + __expf(-(acc[reg] + mO[reg])));
            float other = __shfl_xor(val, 32);  // G <-> sig(M)
            if (quad < 2 && wr) {
                float y = val * other;
                int ch = quad * 4 + reg;
                out[(size_t)(b * 8 + ch) * HW + (size_t)ra * WW + ca] = y;
                ls[reg] += y;
                ls2[reg] += y * y;
            }
        }
    }
#pragma unroll
    for (int m = 1; m < 16; m <<= 1) {
#pragma unroll
        for (int r = 0; r < 4; r++) {
            ls[r] += __shfl_xor(ls[r], m);
            ls2[r] += __shfl_xor(ls2[r], m);
        }
    }
    if (n == 0 && quad < 2) {
        int hash = (blockIdx.x + GX * blockIdx.y + GX * GY * blockIdx.z) & 63;
#pragma unroll
        for (int r = 0; r < 4; r++) {
            atomicAdd(&stats[(quad * 4 + r) * 64 + hash], (double)ls[r]);
            atomicAdd(&stats[(8 + quad * 4 + r) * 64 + hash], (double)ls2[r]);
        }
    }
}

// ---------------------------------------------------------------------------
// k_normS: per-block inline stats reduction (8KB, L2-hot) + grid-stride norm.
// Replaces the separate k_stats dispatch.
// ---------------------------------------------------------------------------
__global__ __launch_bounds__(256) void k_normS(float* __restrict__ out,
                                               const double* __restrict__ stats,
                                               const float* __restrict__ gamma,
                                               const float* __restrict__ beta) {
    __shared__ double red[16][16];
    __shared__ float ssl[16];
    int t = threadIdx.x;
    int row = t >> 4, col = t & 15;
    double s = stats[row * 64 + col] + stats[row * 64 + col + 16] +
               stats[row * 64 + col + 32] + stats[row * 64 + col + 48];
    red[row][col] = s;
    __syncthreads();
    if (t < 16) {
        double tot = 0.0;
#pragma unroll
        for (int i = 0; i < 16; i++) tot += red[t][i];
        red[t][0] = tot;
    }
    __syncthreads();
    if (t < 8) {
        double N = (double)NPX;
        double mean = red[t][0] / N;
        double var = red[8 + t][0] / N - mean * mean;
        double scale = (double)gamma[t] / sqrt(var + 1e-5);
        ssl[t] = (float)scale;
        ssl[8 + t] = (float)((double)beta[t] - mean * scale);
    }
    __syncthreads();
    const int total = (BN * 8 * HW) / 4;
    for (int i = blockIdx.x * 256 + t; i < total; i += 2048 * 256) {
        int ch = (i / 22500) & 7;   // (i*4)/HW
        float sc = ssl[ch], sh = ssl[8 + ch];
        float4* p = (float4*)out + i;
        float4 v = *p;
        v.x = v.x * sc + sh;
        v.y = v.y * sc + sh;
        v.z = v.z * sc + sh;
        v.w = v.w * sc + sh;
        *p = v;
    }
}

// ===========================================================================
// ============ fallback (tiny workspace) kernels ============================
// ===========================================================================
__global__ void k_pool5(const float* __restrict__ x, unsigned short* __restrict__ p5i) {
    int id = blockIdx.x * 256 + threadIdx.x;
    int bc = id / 3600, cell = id % 3600;
    int b = bc >> 3, c = bc & 7;
    int pi = cell / 60, pj = cell % 60;
    const float* rp = x + (size_t)bc * HW + pi * 5 * WW + pj * 5;
    float s = 0.f;
#pragma unroll
    for (int u = 0; u < 5; u++)
#pragma unroll
        for (int v = 0; v < 5; v++) s += rp[u * WW + v];
    p5i[((size_t)b * 3600 + cell) * 8 + c] = (unsigned short)f2bf(s * 0.04f);
}

__global__ void k_poolD(const unsigned short* __restrict__ p5i,
                        unsigned short* __restrict__ p10i,
                        unsigned short* __restrict__ p15i) {
    int id = blockIdx.x * 256 + threadIdx.x;
    if (id < 230400) {
        int bc = id / 900, cell = id % 900;
        int b = bc >> 3, c = bc & 7;
        int pi = cell / 30, pj = cell % 30;
        const unsigned short* base = p5i + ((size_t)b * 3600) * 8 + c;
        float s = bf2f(base[((2 * pi) * 60 + 2 * pj) * 8]) +
                  bf2f(base[((2 * pi) * 60 + 2 * pj + 1) * 8]) +
                  bf2f(base[((2 * pi + 1) * 60 + 2 * pj) * 8]) +
                  bf2f(base[((2 * pi + 1) * 60 + 2 * pj + 1) * 8]);
        p10i[((size_t)b * 900 + cell) * 8 + c] = (unsigned short)f2bf(s * 0.25f);
    } else if (id < 332800) {
        int id2 = id - 230400;
        int bc = id2 / 400, cell = id2 % 400;
        int b = bc >> 3, c = bc & 7;
        int pi = cell / 20, pj = cell % 20;
        const unsigned short* base = p5i + ((size_t)b * 3600) * 8 + c;
        float s = 0.f;
#pragma unroll
        for (int u = 0; u < 3; u++)
#pragma unroll
            for (int v = 0; v < 3; v++)
                s += bf2f(base[((3 * pi + u) * 60 + 3 * pj + v) * 8]);
        p15i[((size_t)b * 400 + cell) * 8 + c] = (unsigned short)f2bf(s * (1.f / 9.f));
    }
}

template <int K, int PW>
__device__ __forceinline__ void up_load(const unsigned short* __restrict__ pooled,
                                        int b, int r0, int c0, int t, uint4* v) {
#pragma unroll
    for (int it = 0; it < 3; it++) {
        int idx = t + 256 * it;
        uint4 val = {0u, 0u, 0u, 0u};
        if (idx < XPX) {
            int i = idx / 36, j = idx - i * 36;
            int ra = r0 - 2 + i, ca = c0 - 2 + j;
            if (ra >= 0 && ra < HH && ca >= 0 && ca < WW) {
                int pi = (int)((unsigned)ra / K);
                int pj = (int)((unsigned)ca / K);
                val = *(const uint4*)&pooled[((size_t)b * (PW * PW) + pi * PW + pj) * 8];
            }
        }
        v[it] = val;
    }
}

__device__ __forceinline__ void up_store(short* xuU, int t, const uint4* v) {
#pragma unroll
    for (int it = 0; it < 3; it++) {
        int idx = t + 256 * it;
        if (idx < XPX) *(uint4*)&xuU[idx * 8] = v[it];
    }
}

__device__ __forceinline__ void c_phase(const short* xuX, const short* xuU,
                                        short* cwP,
                                        const unsigned short* __restrict__ cBs,
                                        const float* __restrict__ bias,
                                        int r0, int c0, int lane, int wid, bool edge) {
    const int n = lane & 15, quad = lane >> 4;
    const int qh = quad >> 1, ql = quad & 1;
    const short* xbase = ql ? xuU : xuX;
    bfrag wfr[5];
    int dpoff[5];
#pragma unroll
    for (int km = 0; km < 5; km++) {
        int tapw = km * 2 + qh;
        int tapa = (tapw > 8) ? 8 : tapw;
        wfr[km] = *(const bfrag*)&cBs[(n * 10 + tapw) * 16 + ql * 8];
        dpoff[km] = ((tapa / 3) * 36 + tapa % 3) * 8;
    }
    float bO[4];
#pragma unroll
    for (int r = 0; r < 4; r++) bO[r] = bias[(quad & 1) * 4 + r];

    for (int g = wid; g < 39; g += 4) {
        int px = g * 16 + n;
        if (px > 611) px = 611;
        int rp = (int)((unsigned)px / 34u);
        int cp = px - rp * 34;
        int pb = (rp * 36 + cp) * 8;
        f32x4 acc = {0.f, 0.f, 0.f, 0.f};
#pragma unroll
        for (int km = 0; km < 5; km++)
            acc = __builtin_amdgcn_mfma_f32_16x16x32_bf16(
                wfr[km], *(const bfrag*)&xbase[pb + dpoff[km]], acc, 0, 0, 0);
        if (quad < 2) {
            bf16x4 pk;
#pragma unroll
            for (int r = 0; r < 4; r++) pk[r] = (__bf16)(acc[r] + bO[r]);
            if (edge) {
                int ra = r0 - 1 + rp, ca = c0 - 1 + cp;
                if (ra < 0 || ra >= HH || ca < 0 || ca >= WW) {
#pragma unroll
                    for (int r = 0; r < 4; r++) pk[r] = (__bf16)0.f;
                }
            }
            *(bf16x4*)&cwP[px * 8 + quad * 4] = pk;
        }
    }
}

__global__ __launch_bounds__(256, 3) void k_fused_fb(
    const float* __restrict__ x,
    const unsigned short* __restrict__ p5i, const unsigned short* __restrict__ p10i,
    const unsigned short* __restrict__ p15i,
    const unsigned short* __restrict__ cBg, const unsigned short* __restrict__ gBg,
    const float* __restrict__ b5, const float* __restrict__ b10, const float* __restrict__ b15,
    const float* __restrict__ gb, const float* __restrict__ mb,
    float* __restrict__ out, double* __restrict__ stats) {
    __shared__ __align__(16) short xuX[XPX * 8];
    __shared__ __align__(16) short xuU[XPX * 8];
    __shared__ __align__(16) short cwS[3 * CWSTRIDE];

    const int b = blockIdx.z;
    const int r0 = blockIdx.y * 16, c0 = blockIdx.x * 32;
    const int t = threadIdx.x, lane = t & 63, wid = t >> 6;
    const bool edge = (blockIdx.x == 0) | (blockIdx.x == GX - 1) |
                      (blockIdx.y == 0) | (blockIdx.y == GY - 1);

    uint4 upv[3];
    up_load<5, 60>(p5i, b, r0, c0, t, upv);

    for (int idx = t; idx < 1440; idx += 256) {
        int cp = idx / 360, rem = idx % 360;
        int i = rem / 18, jp = rem % 18;
        int j = 2 * jp;
        int ra = r0 - 2 + i, ca = c0 - 2 + j;
        float2 v0 = {0.f, 0.f}, v1 = {0.f, 0.f};
        if (ra >= 0 && ra < HH && ca >= 0 && ca <= WW - 2) {
            size_t base = ((size_t)(b * 8 + 2 * cp) * HH + ra) * WW + ca;
            v0 = *(const float2*)&x[base];
            v1 = *(const float2*)&x[base + HW];
        }
        unsigned pA = (unsigned short)f2bf(v0.x) | ((unsigned)(unsigned short)f2bf(v1.x) << 16);
        unsigned pB = (unsigned short)f2bf(v0.y) | ((unsigned)(unsigned short)f2bf(v1.y) << 16);
        int px = i * 36 + j;
        *(unsigned*)&xuX[px * 8 + 2 * cp] = pA;
        *(unsigned*)&xuX[(px + 1) * 8 + 2 * cp] = pB;
    }
    up_store(xuU, t, upv);
    __syncthreads();

    c_phase(xuX, xuU, cwS, cBg, b5, r0, c0, lane, wid, edge);
    up_load<10, 30>(p10i, b, r0, c0, t, upv);
    __syncthreads();
    up_store(xuU, t, upv);
    __syncthreads();

    c_phase(xuX, xuU, cwS + CWSTRIDE, cBg + 2560, b10, r0, c0, lane, wid, edge);
    up_load<15, 20>(p15i, b, r0, c0, t, upv);
    __syncthreads();
    up_store(xuU, t, upv);
    __syncthreads();

    c_phase(xuX, xuU, cwS + 2 * CWSTRIDE, cBg + 5120, b15, r0, c0, lane, wid, edge);
    __syncthreads();

    const int n = lane & 15, quad = lane >> 4;
    bfrag gfr[7];
    int goff[7];
#pragma unroll
    for (int km = 0; km < 7; km++) {
        int blkw = km * 4 + quad;
        int blka = (blkw > 26) ? 26 : blkw;
        gfr[km] = *(const bfrag*)&gBg[(n * 28 + blkw) * 8];
        int tap = blka / 3, cig = blka - tap * 3;
        goff[km] = cig * CWSTRIDE + ((tap / 3) * 34 + tap % 3) * 8;
    }
    float gO[4], mO[4];
#pragma unroll
    for (int r = 0; r < 4; r++) {
        gO[r] = gb[(quad & 1) * 4 + r];
        mO[r] = mb[(quad & 1) * 4 + r];
    }
    float ls[4] = {0.f, 0.f, 0.f, 0.f}, ls2[4] = {0.f, 0.f, 0.f, 0.f};

    for (int g = wid; g < 32; g += 4) {
        int px = g * 16 + n;
        int rr = px >> 5, cc = px & 31;
        int off0 = (rr * 34 + cc) * 8;
        f32x4 acc = {0.f, 0.f, 0.f, 0.f};
#pragma unroll
        for (int km = 0; km < 7; km++)
            acc = __builtin_amdgcn_mfma_f32_16x16x32_bf16(
                gfr[km], *(const bfrag*)&cwS[off0 + goff[km]], acc, 0, 0, 0);
        int ra = r0 + rr, ca = c0 + cc;
        bool wr = !edge || (ra < HH && ca < WW);
#pragma unroll
        for (int reg = 0; reg < 4; reg++) {
            float val;
            if (quad < 2) val = acc[reg] + gO[reg];
            else          val = __builtin_amdgcn_rcpf(1.f + __expf(-(acc[reg] + mO[reg])));
            float other = __shfl_xor(val, 32);
            if (quad < 2 && wr) {
                float y = val * other;
                int ch = quad * 4 + reg;
                out[(size_t)(b * 8 + ch) * HW + (size_t)ra * WW + ca] = y;
                ls[reg] += y;
                ls2[reg] += y * y;
            }
        }
    }
#pragma unroll
    for (int m = 1; m < 16; m <<= 1) {
#pragma unroll
        for (int r = 0; r < 4; r++) {
            ls[r] += __shfl_xor(ls[r], m);
            ls2[r] += __shfl_xor(ls2[r], m);
        }
    }
    if (n == 0 && quad < 2) {
        int hash = (blockIdx.x + GX * blockIdx.y + GX * GY * blockIdx.z) & 63;
#pragma unroll
        for (int r = 0; r < 4; r++) {
            atomicAdd(&stats[(quad * 4 + r) * 64 + hash], (double)ls[r]);
            atomicAdd(&stats[(8 + quad * 4 + r) * 64 + hash], (double)ls2[r]);
        }
    }
}

__global__ void k_stats(const double* __restrict__ stats, const float* __restrict__ gamma,
                        const float* __restrict__ beta, float* __restrict__ ss) {
    __shared__ double red[16][16];
    int t = threadIdx.x;
    int row = t >> 4, col = t & 15;
    double s = stats[row * 64 + col] + stats[row * 64 + col + 16] +
               stats[row * 64 + col + 32] + stats[row * 64 + col + 48];
    red[row][col] = s;
    __syncthreads();
    if (t < 16) {
        double tot = 0.0;
#pragma unroll
        for (int i = 0; i < 16; i++) tot += red[t][i];
        red[t][0] = tot;
    }
    __syncthreads();
    if (t < 8) {
        double N = (double)NPX;
        double mean = red[t][0] / N;
        double var = red[8 + t][0] / N - mean * mean;
        double scale = (double)gamma[t] / sqrt(var + 1e-5);
        ss[t] = (float)scale;
        ss[8 + t] = (float)((double)beta[t] - mean * scale);
    }
}

__global__ void k_norm(float* __restrict__ out, const float* __restrict__ ss) {
    int i = blockIdx.x * 256 + threadIdx.x;
    if (i < (BN * 8 * HW) / 4) {
        int plane = (i * 4) / HW;
        int ch = plane & 7;
        float sc = ss[ch], sh = ss[8 + ch];
        float4* p = (float4*)out + i;
        float4 v = *p;
        v.x = v.x * sc + sh;
        v.y = v.y * sc + sh;
        v.z = v.z * sc + sh;
        v.w = v.w * sc + sh;
        *p = v;
    }
}

// ---------------------------------------------------------------------------
extern "C" void kernel_launch(void* const* d_in, const int* in_sizes, int n_in,
                              void* d_out, int out_size, void* d_ws, size_t ws_size,
                              hipStream_t stream) {
    const float* x = (const float*)d_in[0];
    const float* w5 = (const float*)d_in[1];
    const float* b5 = (const float*)d_in[2];
    const float* w10 = (const float*)d_in[3];
    const float* b10 = (const float*)d_in[4];
    const float* w15 = (const float*)d_in[5];
    const float* b15 = (const float*)d_in[6];
    const float* gw = (const float*)d_in[7];
    const float* gb = (const float*)d_in[8];
    const float* mw = (const float*)d_in[9];
    const float* mb = (const float*)d_in[10];
    const float* gamma = (const float*)d_in[11];
    const float* beta = (const float*)d_in[12];
    float* out = (float*)d_out;

    unsigned short* p5i = (unsigned short*)((char*)d_ws + P5I_BYTE_OFF);
    unsigned short* p10i = (unsigned short*)((char*)d_ws + P10I_BYTE_OFF);
    unsigned short* p15i = (unsigned short*)((char*)d_ws + P15I_BYTE_OFF);
    short* cBg = (short*)((char*)d_ws + CWB_BYTE_OFF);
    short* gBg = (short*)((char*)d_ws + GWB_BYTE_OFF);
    double* stats = (double*)((char*)d_ws + STAT_BYTE_OFF);
    float* ss = (float*)((char*)d_ws + SS_BYTE_OFF);
    unsigned short* xbf = (unsigned short*)((char*)d_ws + XBF_BYTE_OFF);

    dim3 grid(GX, GY, BN);
    if (ws_size >= XBF_END) {
        k_prepAll<<<dim3(100, 32), 256, 0, stream>>>(x, xbf, p5i, p10i, p15i,
                                                     w5, w10, w15, gw, mw,
                                                     cBg, gBg, stats);
        k_fused5<<<grid, 256, 0, stream>>>(xbf, p5i, p10i, p15i,
                                           (const unsigned short*)cBg, (const unsigned short*)gBg,
                                           b5, b10, b15, gb, mb, out, stats);
        k_normS<<<2048, 256, 0, stream>>>(out, stats, gamma, beta);
    } else {
        k_setup<<<1, 256, 0, stream>>>(w5, w10, w15, gw, mw, cBg, gBg, stats);
        k_pool5<<<3600, 256, 0, stream>>>(x, p5i);
        k_poolD<<<1300, 256, 0, stream>>>(p5i, p10i, p15i);
        k_fused_fb<<<grid, 256, 0, stream>>>(x, p5i, p10i, p15i,
                                             (const unsigned short*)cBg, (const unsigned short*)gBg,
                                             b5, b10, b15, gb, mb, out, stats);
        k_stats<<<1, 256, 0, stream>>>(stats, gamma, beta, ss);
        k_norm<<<(BN * 8 * HW / 4 + 255) / 256, 256, 0, stream>>>(out, ss);
    }
}